// Round 1
// baseline (3799.926 us; speedup 1.0000x reference)
//
#include <hip/hip_runtime.h>
#include <math.h>

#define CCH 48
#define SDIM 32
#define SVOL (SDIM*SDIM*SDIM)
#define NB 2

// ---------------- LayerNorm over C ----------------
__global__ void ln_kernel(const float* __restrict__ x, const float* __restrict__ ln_s,
                          const float* __restrict__ ln_b, float* __restrict__ xn) {
    int s = blockIdx.x * 256 + threadIdx.x;
    int b = blockIdx.y;
    const float* xb = x + (size_t)b * CCH * SVOL + s;
    float v[CCH];
    float mu = 0.f;
    #pragma unroll
    for (int c = 0; c < CCH; c++) { v[c] = xb[c * SVOL]; mu += v[c]; }
    mu *= (1.0f / CCH);
    float var = 0.f;
    #pragma unroll
    for (int c = 0; c < CCH; c++) { float d = v[c] - mu; var += d * d; }
    var *= (1.0f / CCH);
    float inv = rsqrtf(var + 1e-5f);
    float* o = xn + (size_t)b * CCH * SVOL + s;
    #pragma unroll
    for (int c = 0; c < CCH; c++) o[c * SVOL] = (v[c] - mu) * inv * ln_s[c] + ln_b[c];
}

// ---------------- 1x1x1 conv + exact GELU ----------------
__global__ void p1_gelu_kernel(const float* __restrict__ xn, const float* __restrict__ w,
                               const float* __restrict__ bias, float* __restrict__ u) {
    __shared__ float ws[CCH * CCH];   // transposed: ws[ci*48+o]
    __shared__ float bs[CCH];
    int tid = threadIdx.x;
    for (int i = tid; i < CCH * CCH; i += 256) { int o = i / CCH, ci = i % CCH; ws[ci * CCH + o] = w[o * CCH + ci]; }
    if (tid < CCH) bs[tid] = bias[tid];
    __syncthreads();
    int s = blockIdx.x * 256 + tid; int b = blockIdx.y;
    const float* xb = xn + (size_t)b * CCH * SVOL + s;
    float acc[CCH];
    #pragma unroll
    for (int o = 0; o < CCH; o++) acc[o] = bs[o];
    for (int c = 0; c < CCH; c++) {
        float v = xb[c * SVOL];
        #pragma unroll
        for (int o = 0; o < CCH; o++) acc[o] += ws[c * CCH + o] * v;
    }
    float* ub = u + (size_t)b * CCH * SVOL + s;
    #pragma unroll
    for (int o = 0; o < CCH; o++) {
        float a = acc[o];
        ub[o * SVOL] = 0.5f * a * (1.0f + erff(a * 0.70710678118654752f));
    }
}

// ---------------- depthwise 5x5x5 pad 2 ----------------
__global__ void dw5_kernel(const float* __restrict__ in, const float* __restrict__ w,
                           const float* __restrict__ bias, float* __restrict__ out) {
    __shared__ float ws[125];
    int tid = threadIdx.x;
    int c = blockIdx.y, b = blockIdx.z;
    if (tid < 125) ws[tid] = w[c * 125 + tid];
    __syncthreads();
    int s = blockIdx.x * 256 + tid;
    int z = s >> 10, y = (s >> 5) & 31, xx = s & 31;
    const float* ib = in + ((size_t)b * CCH + c) * SVOL;
    float acc = bias[c];
    for (int dz = -2; dz <= 2; dz++) {
        int zz = z + dz; if (zz < 0 || zz >= 32) continue;
        for (int dy = -2; dy <= 2; dy++) {
            int yy = y + dy; if (yy < 0 || yy >= 32) continue;
            #pragma unroll
            for (int dx = -2; dx <= 2; dx++) {
                int xv = xx + dx; if (xv < 0 || xv >= 32) continue;
                acc += ws[((dz + 2) * 5 + (dy + 2)) * 5 + (dx + 2)] * ib[(zz * 32 + yy) * 32 + xv];
            }
        }
    }
    out[((size_t)b * CCH + c) * SVOL + s] = acc;
}

// ---------------- depthwise 7x7x7 dil 3 pad 9 ----------------
__global__ void dw7_kernel(const float* __restrict__ in, const float* __restrict__ w,
                           const float* __restrict__ bias, float* __restrict__ out) {
    __shared__ float ws[343];
    int tid = threadIdx.x;
    int c = blockIdx.y, b = blockIdx.z;
    for (int i = tid; i < 343; i += 256) ws[i] = w[c * 343 + i];
    __syncthreads();
    int s = blockIdx.x * 256 + tid;
    int z = s >> 10, y = (s >> 5) & 31, xx = s & 31;
    const float* ib = in + ((size_t)b * CCH + c) * SVOL;
    float acc = bias[c];
    for (int tz = 0; tz < 7; tz++) {
        int zz = z + 3 * (tz - 3); if (zz < 0 || zz >= 32) continue;
        for (int ty = 0; ty < 7; ty++) {
            int yy = y + 3 * (ty - 3); if (yy < 0 || yy >= 32) continue;
            #pragma unroll
            for (int tx = 0; tx < 7; tx++) {
                int xv = xx + 3 * (tx - 3); if (xv < 0 || xv >= 32) continue;
                acc += ws[(tz * 7 + ty) * 7 + tx] * ib[(zz * 32 + yy) * 32 + xv];
            }
        }
    }
    out[((size_t)b * CCH + c) * SVOL + s] = acc;
}

// ---------------- offset conv 3x3x3: 48 -> 81 ----------------
__global__ void offconv_kernel(const float* __restrict__ a1, const float* __restrict__ w,
                               const float* __restrict__ bias, float* __restrict__ off) {
    __shared__ float ws[CCH * 81];  // ws[ci*81+o]
    int tid = threadIdx.x;
    int s = blockIdx.x * 256 + tid; int b = blockIdx.y;
    int z = s >> 10, y = (s >> 5) & 31, xx = s & 31;
    const float* ib = a1 + (size_t)b * CCH * SVOL;
    float acc[81];
    #pragma unroll
    for (int o = 0; o < 81; o++) acc[o] = bias[o];
    for (int tap = 0; tap < 27; tap++) {
        __syncthreads();
        for (int i = tid; i < CCH * 81; i += 256) {
            int o = i / CCH, ci = i % CCH;
            ws[ci * 81 + o] = w[(o * CCH + ci) * 27 + tap];
        }
        __syncthreads();
        int dz = tap / 9 - 1, dy = (tap / 3) % 3 - 1, dx = tap % 3 - 1;
        int zz = z + dz, yy = y + dy, xv = xx + dx;
        bool ok = (zz >= 0 && zz < 32 && yy >= 0 && yy < 32 && xv >= 0 && xv < 32);
        if (ok) {
            int si = (zz * 32 + yy) * 32 + xv;
            for (int ci = 0; ci < CCH; ci++) {
                float v = ib[ci * SVOL + si];
                #pragma unroll
                for (int o = 0; o < 81; o++) acc[o] += ws[ci * 81 + o] * v;
            }
        }
    }
    float* ob = off + (size_t)b * 81 * SVOL + s;
    #pragma unroll
    for (int o = 0; o < 81; o++) ob[o * SVOL] = acc[o];
}

// ---------------- deformable conv 3x3x3 ----------------
__global__ void deform_kernel(const float* __restrict__ a1, const float* __restrict__ off,
                              const float* __restrict__ dcw, const float* __restrict__ dcb,
                              float* __restrict__ out) {
    __shared__ float ws[CCH * CCH];  // ws[ci*48+o]
    int tid = threadIdx.x;
    int s = blockIdx.x * 256 + tid; int b = blockIdx.y;
    int z = s >> 10, y = (s >> 5) & 31, xx = s & 31;
    const float* ib = a1 + (size_t)b * CCH * SVOL;
    const float* ob = off + (size_t)b * 81 * SVOL + s;
    float acc[CCH];
    #pragma unroll
    for (int o = 0; o < CCH; o++) acc[o] = dcb[o];
    for (int k = 0; k < 27; k++) {
        __syncthreads();
        for (int i = tid; i < CCH * CCH; i += 256) {
            int o = i / CCH, ci = i % CCH;
            ws[ci * CCH + o] = dcw[(o * CCH + ci) * 27 + k];
        }
        __syncthreads();
        int kd = k / 9 - 1, kh = (k / 3) % 3 - 1, kw = k % 3 - 1;
        float zf = (float)z + (float)kd + ob[(k * 3 + 0) * SVOL];
        float yf = (float)y + (float)kh + ob[(k * 3 + 1) * SVOL];
        float xf = (float)xx + (float)kw + ob[(k * 3 + 2) * SVOL];
        float z0 = floorf(zf), y0 = floorf(yf), x0 = floorf(xf);
        float tz = zf - z0, ty = yf - y0, tx = xf - x0;
        int iz0 = (int)z0, iy0 = (int)y0, ix0 = (int)x0;
        float cw[8]; int cidx[8];
        #pragma unroll
        for (int corner = 0; corner < 8; corner++) {
            int dz = corner >> 2, dy = (corner >> 1) & 1, dx = corner & 1;
            int zi = iz0 + dz, yi = iy0 + dy, xi = ix0 + dx;
            bool valid = (zi >= 0 && zi < 32 && yi >= 0 && yi < 32 && xi >= 0 && xi < 32);
            float wgt = (dz ? tz : 1.f - tz) * (dy ? ty : 1.f - ty) * (dx ? tx : 1.f - tx);
            cw[corner] = valid ? wgt : 0.f;
            int zc = min(max(zi, 0), 31), yc = min(max(yi, 0), 31), xc = min(max(xi, 0), 31);
            cidx[corner] = (zc * 32 + yc) * 32 + xc;
        }
        for (int ci = 0; ci < CCH; ci++) {
            const float* p = ib + ci * SVOL;
            float val = 0.f;
            #pragma unroll
            for (int corner = 0; corner < 8; corner++) val += cw[corner] * p[cidx[corner]];
            #pragma unroll
            for (int o = 0; o < CCH; o++) acc[o] += ws[ci * CCH + o] * val;
        }
    }
    float* op = out + (size_t)b * CCH * SVOL + s;
    #pragma unroll
    for (int o = 0; o < CCH; o++) op[o * SVOL] = acc[o];
}

// ---------------- fused: c1(1x1x1) -> gate(*u) -> p2(1x1x1) -> +shortcut -> skip ----------------
__global__ void gate_kernel(const float* __restrict__ dc, const float* __restrict__ u,
                            const float* __restrict__ xn, const float* __restrict__ x,
                            const float* __restrict__ c1w, const float* __restrict__ c1b,
                            const float* __restrict__ p2w, const float* __restrict__ p2b,
                            const float* __restrict__ gamma, float* __restrict__ skip) {
    __shared__ float w1[CCH * CCH];
    __shared__ float w2[CCH * CCH];
    __shared__ float b1s[CCH], b2s[CCH], gs[CCH];
    int tid = threadIdx.x;
    for (int i = tid; i < CCH * CCH; i += 256) {
        int o = i / CCH, ci = i % CCH;
        w1[ci * CCH + o] = c1w[o * CCH + ci];
        w2[ci * CCH + o] = p2w[o * CCH + ci];
    }
    if (tid < CCH) { b1s[tid] = c1b[tid]; b2s[tid] = p2b[tid]; gs[tid] = gamma[tid]; }
    __syncthreads();
    int s = blockIdx.x * 256 + tid; int b = blockIdx.y;
    size_t base = (size_t)b * CCH * SVOL + s;
    float a2[CCH];
    #pragma unroll
    for (int o = 0; o < CCH; o++) a2[o] = b1s[o];
    for (int ci = 0; ci < CCH; ci++) {
        float v = dc[base + ci * SVOL];
        #pragma unroll
        for (int o = 0; o < CCH; o++) a2[o] += w1[ci * CCH + o] * v;
    }
    #pragma unroll
    for (int o = 0; o < CCH; o++) a2[o] *= u[base + o * SVOL];
    float v3[CCH];
    #pragma unroll
    for (int o = 0; o < CCH; o++) v3[o] = b2s[o];
    for (int ci = 0; ci < CCH; ci++) {
        float v = a2[ci];
        #pragma unroll
        for (int o = 0; o < CCH; o++) v3[o] += w2[ci * CCH + o] * v;
    }
    #pragma unroll
    for (int o = 0; o < CCH; o++) {
        float vv = v3[o] + xn[base + o * SVOL];           // proj_2 + shortcut
        skip[base + o * SVOL] = x[base + o * SVOL] + gs[o] * vv;  // tok + gamma*epa
    }
}

// ---------------- u1: 3x3x3 conv (no bias) + BN1 + LeakyReLU ----------------
__global__ void u1_kernel(const float* __restrict__ in, const float* __restrict__ w,
                          const float* __restrict__ bs, const float* __restrict__ bb,
                          const float* __restrict__ bm, const float* __restrict__ bv,
                          float* __restrict__ out) {
    __shared__ float ws[CCH * CCH];
    int tid = threadIdx.x;
    int s = blockIdx.x * 256 + tid; int b = blockIdx.y;
    int z = s >> 10, y = (s >> 5) & 31, xx = s & 31;
    const float* ib = in + (size_t)b * CCH * SVOL;
    float acc[CCH];
    #pragma unroll
    for (int o = 0; o < CCH; o++) acc[o] = 0.f;
    for (int tap = 0; tap < 27; tap++) {
        __syncthreads();
        for (int i = tid; i < CCH * CCH; i += 256) {
            int o = i / CCH, ci = i % CCH;
            ws[ci * CCH + o] = w[(o * CCH + ci) * 27 + tap];
        }
        __syncthreads();
        int dz = tap / 9 - 1, dy = (tap / 3) % 3 - 1, dx = tap % 3 - 1;
        int zz = z + dz, yy = y + dy, xv = xx + dx;
        bool ok = (zz >= 0 && zz < 32 && yy >= 0 && yy < 32 && xv >= 0 && xv < 32);
        if (ok) {
            int si = (zz * 32 + yy) * 32 + xv;
            for (int ci = 0; ci < CCH; ci++) {
                float v = ib[ci * SVOL + si];
                #pragma unroll
                for (int o = 0; o < CCH; o++) acc[o] += ws[ci * CCH + o] * v;
            }
        }
    }
    float* op = out + (size_t)b * CCH * SVOL + s;
    #pragma unroll
    for (int o = 0; o < CCH; o++) {
        float inv = rsqrtf(bv[o] + 1e-5f);
        float h = (acc[o] - bm[o]) * (bs[o] * inv) + bb[o];
        op[o * SVOL] = h >= 0.f ? h : 0.01f * h;
    }
}

// ---------------- u2: 3x3x3 conv + BN2 + (+skip) + LeakyReLU + pr(1x1x1) + residual ----------------
__global__ void u2_final_kernel(const float* __restrict__ h1, const float* __restrict__ skip,
                                const float* __restrict__ w,
                                const float* __restrict__ bs, const float* __restrict__ bb,
                                const float* __restrict__ bm, const float* __restrict__ bv,
                                const float* __restrict__ prw, const float* __restrict__ prb,
                                float* __restrict__ out) {
    __shared__ float ws[CCH * CCH];
    __shared__ float pw[CCH * CCH];
    int tid = threadIdx.x;
    for (int i = tid; i < CCH * CCH; i += 256) {
        int o = i / CCH, ci = i % CCH;
        pw[ci * CCH + o] = prw[o * CCH + ci];
    }
    int s = blockIdx.x * 256 + tid; int b = blockIdx.y;
    int z = s >> 10, y = (s >> 5) & 31, xx = s & 31;
    const float* ib = h1 + (size_t)b * CCH * SVOL;
    float acc[CCH];
    #pragma unroll
    for (int o = 0; o < CCH; o++) acc[o] = 0.f;
    for (int tap = 0; tap < 27; tap++) {
        __syncthreads();
        for (int i = tid; i < CCH * CCH; i += 256) {
            int o = i / CCH, ci = i % CCH;
            ws[ci * CCH + o] = w[(o * CCH + ci) * 27 + tap];
        }
        __syncthreads();
        int dz = tap / 9 - 1, dy = (tap / 3) % 3 - 1, dx = tap % 3 - 1;
        int zz = z + dz, yy = y + dy, xv = xx + dx;
        bool ok = (zz >= 0 && zz < 32 && yy >= 0 && yy < 32 && xv >= 0 && xv < 32);
        if (ok) {
            int si = (zz * 32 + yy) * 32 + xv;
            for (int ci = 0; ci < CCH; ci++) {
                float v = ib[ci * SVOL + si];
                #pragma unroll
                for (int o = 0; o < CCH; o++) acc[o] += ws[ci * CCH + o] * v;
            }
        }
    }
    size_t base = (size_t)b * CCH * SVOL + s;
    // BN2 + skip + leaky -> attn (reuse acc)
    #pragma unroll
    for (int o = 0; o < CCH; o++) {
        float inv = rsqrtf(bv[o] + 1e-5f);
        float h = (acc[o] - bm[o]) * (bs[o] * inv) + bb[o];
        float a = h + skip[base + o * SVOL];
        acc[o] = a >= 0.f ? a : 0.01f * a;
    }
    float res[CCH];
    #pragma unroll
    for (int o = 0; o < CCH; o++) res[o] = prb[o];
    for (int ci = 0; ci < CCH; ci++) {
        float v = acc[ci];
        #pragma unroll
        for (int o = 0; o < CCH; o++) res[o] += pw[ci * CCH + o] * v;
    }
    #pragma unroll
    for (int o = 0; o < CCH; o++) out[base + o * SVOL] = skip[base + o * SVOL] + res[o];
}

extern "C" void kernel_launch(void* const* d_in, const int* in_sizes, int n_in,
                              void* d_out, int out_size, void* d_ws, size_t ws_size,
                              hipStream_t stream) {
    (void)in_sizes; (void)n_in; (void)out_size; (void)ws_size;
    const float* x     = (const float*)d_in[0];
    const float* ln_s  = (const float*)d_in[1];
    const float* ln_b  = (const float*)d_in[2];
    const float* gamma = (const float*)d_in[3];
    const float* p1_w  = (const float*)d_in[4];
    const float* p1_b  = (const float*)d_in[5];
    const float* p2_w  = (const float*)d_in[6];
    const float* p2_b  = (const float*)d_in[7];
    const float* c0_w  = (const float*)d_in[8];
    const float* c0_b  = (const float*)d_in[9];
    const float* cs_w  = (const float*)d_in[10];
    const float* cs_b  = (const float*)d_in[11];
    const float* off_w = (const float*)d_in[12];
    const float* off_b = (const float*)d_in[13];
    const float* dc_w  = (const float*)d_in[14];
    const float* dc_b  = (const float*)d_in[15];
    const float* c1_w  = (const float*)d_in[16];
    const float* c1_b  = (const float*)d_in[17];
    const float* u1_w  = (const float*)d_in[18];
    const float* bn1_s = (const float*)d_in[19];
    const float* bn1_b = (const float*)d_in[20];
    const float* bn1_m = (const float*)d_in[21];
    const float* bn1_v = (const float*)d_in[22];
    const float* u2_w  = (const float*)d_in[23];
    const float* bn2_s = (const float*)d_in[24];
    const float* bn2_b = (const float*)d_in[25];
    const float* bn2_m = (const float*)d_in[26];
    const float* bn2_v = (const float*)d_in[27];
    const float* pr_w  = (const float*)d_in[28];
    const float* pr_b  = (const float*)d_in[29];
    float* out = (float*)d_out;

    float* wsf = (float*)d_ws;
    const size_t TS = (size_t)NB * CCH * SVOL;   // 3,145,728 floats
    float* xn   = out;            // reuse d_out as xn scratch (dead before final write)
    float* ubuf = wsf;            // gelu output u, later h1
    float* bufA = wsf + TS;       // dw5 out, later deform out
    float* bufB = wsf + 2 * TS;   // dw7 out (a1), later skip
    float* offb = wsf + 3 * TS;   // offsets [B,81,S] = 5,308,416 floats
    // total ws use: 3*TS + B*81*S = 14,745,600 floats = 59.0 MB

    dim3 blk(256);
    dim3 gpos(SVOL / 256, NB);
    dim3 gdw(SVOL / 256, CCH, NB);

    hipLaunchKernelGGL(ln_kernel,       gpos, blk, 0, stream, x, ln_s, ln_b, xn);
    hipLaunchKernelGGL(p1_gelu_kernel,  gpos, blk, 0, stream, xn, p1_w, p1_b, ubuf);
    hipLaunchKernelGGL(dw5_kernel,      gdw,  blk, 0, stream, ubuf, c0_w, c0_b, bufA);
    hipLaunchKernelGGL(dw7_kernel,      gdw,  blk, 0, stream, bufA, cs_w, cs_b, bufB);
    hipLaunchKernelGGL(offconv_kernel,  gpos, blk, 0, stream, bufB, off_w, off_b, offb);
    hipLaunchKernelGGL(deform_kernel,   gpos, blk, 0, stream, bufB, offb, dc_w, dc_b, bufA);
    hipLaunchKernelGGL(gate_kernel,     gpos, blk, 0, stream, bufA, ubuf, xn, x,
                       c1_w, c1_b, p2_w, p2_b, gamma, bufB);
    hipLaunchKernelGGL(u1_kernel,       gpos, blk, 0, stream, bufB, u1_w,
                       bn1_s, bn1_b, bn1_m, bn1_v, ubuf);
    hipLaunchKernelGGL(u2_final_kernel, gpos, blk, 0, stream, ubuf, bufB, u2_w,
                       bn2_s, bn2_b, bn2_m, bn2_v, pr_w, pr_b, out);
}

// Round 2
// 3406.223 us; speedup vs baseline: 1.1156x; 1.1156x over previous
//
#include <hip/hip_runtime.h>
#include <math.h>

#define CCH 48
#define SDIM 32
#define SVOL (SDIM*SDIM*SDIM)
#define NB 2

// ---------------- LayerNorm over C ----------------
__global__ __launch_bounds__(256)
void ln_kernel(const float* __restrict__ x, const float* __restrict__ ln_s,
               const float* __restrict__ ln_b, float* __restrict__ xn) {
    int s = blockIdx.x * 256 + threadIdx.x;
    int b = blockIdx.y;
    const float* xb = x + (size_t)b * CCH * SVOL + s;
    float v[CCH];
    float mu = 0.f;
    #pragma unroll
    for (int c = 0; c < CCH; c++) { v[c] = xb[c * SVOL]; mu += v[c]; }
    mu *= (1.0f / CCH);
    float var = 0.f;
    #pragma unroll
    for (int c = 0; c < CCH; c++) { float d = v[c] - mu; var += d * d; }
    var *= (1.0f / CCH);
    float inv = rsqrtf(var + 1e-5f);
    float* o = xn + (size_t)b * CCH * SVOL + s;
    #pragma unroll
    for (int c = 0; c < CCH; c++) o[c * SVOL] = (v[c] - mu) * inv * ln_s[c] + ln_b[c];
}

// ---------------- 1x1x1 conv + exact GELU ----------------
__global__ __launch_bounds__(256)
void p1_gelu_kernel(const float* __restrict__ xn, const float* __restrict__ w,
                    const float* __restrict__ bias, float* __restrict__ u) {
    __shared__ float ws[CCH * CCH];   // transposed: ws[ci*48+o]
    __shared__ float bs[CCH];
    int tid = threadIdx.x;
    for (int i = tid; i < CCH * CCH; i += 256) { int o = i / CCH, ci = i % CCH; ws[ci * CCH + o] = w[o * CCH + ci]; }
    if (tid < CCH) bs[tid] = bias[tid];
    __syncthreads();
    int s = blockIdx.x * 256 + tid; int b = blockIdx.y;
    const float* xb = xn + (size_t)b * CCH * SVOL + s;
    float acc[CCH];
    #pragma unroll
    for (int o = 0; o < CCH; o++) acc[o] = bs[o];
    for (int c = 0; c < CCH; c++) {
        float v = xb[c * SVOL];
        #pragma unroll
        for (int o = 0; o < CCH; o++) acc[o] += ws[c * CCH + o] * v;
    }
    float* ub = u + (size_t)b * CCH * SVOL + s;
    #pragma unroll
    for (int o = 0; o < CCH; o++) {
        float a = acc[o];
        ub[o * SVOL] = 0.5f * a * (1.0f + erff(a * 0.70710678118654752f));
    }
}

// ---------------- depthwise 5x5x5 pad 2 ----------------
__global__ __launch_bounds__(256)
void dw5_kernel(const float* __restrict__ in, const float* __restrict__ w,
                const float* __restrict__ bias, float* __restrict__ out) {
    __shared__ float ws[125];
    int tid = threadIdx.x;
    int c = blockIdx.y, b = blockIdx.z;
    if (tid < 125) ws[tid] = w[c * 125 + tid];
    __syncthreads();
    int s = blockIdx.x * 256 + tid;
    int z = s >> 10, y = (s >> 5) & 31, xx = s & 31;
    const float* ib = in + ((size_t)b * CCH + c) * SVOL;
    float acc = bias[c];
    for (int dz = -2; dz <= 2; dz++) {
        int zz = z + dz; if (zz < 0 || zz >= 32) continue;
        for (int dy = -2; dy <= 2; dy++) {
            int yy = y + dy; if (yy < 0 || yy >= 32) continue;
            #pragma unroll
            for (int dx = -2; dx <= 2; dx++) {
                int xv = xx + dx; if (xv < 0 || xv >= 32) continue;
                acc += ws[((dz + 2) * 5 + (dy + 2)) * 5 + (dx + 2)] * ib[(zz * 32 + yy) * 32 + xv];
            }
        }
    }
    out[((size_t)b * CCH + c) * SVOL + s] = acc;
}

// ---------------- depthwise 7x7x7 dil 3 pad 9 ----------------
__global__ __launch_bounds__(256)
void dw7_kernel(const float* __restrict__ in, const float* __restrict__ w,
                const float* __restrict__ bias, float* __restrict__ out) {
    __shared__ float ws[343];
    int tid = threadIdx.x;
    int c = blockIdx.y, b = blockIdx.z;
    for (int i = tid; i < 343; i += 256) ws[i] = w[c * 343 + i];
    __syncthreads();
    int s = blockIdx.x * 256 + tid;
    int z = s >> 10, y = (s >> 5) & 31, xx = s & 31;
    const float* ib = in + ((size_t)b * CCH + c) * SVOL;
    float acc = bias[c];
    for (int tz = 0; tz < 7; tz++) {
        int zz = z + 3 * (tz - 3); if (zz < 0 || zz >= 32) continue;
        for (int ty = 0; ty < 7; ty++) {
            int yy = y + 3 * (ty - 3); if (yy < 0 || yy >= 32) continue;
            #pragma unroll
            for (int tx = 0; tx < 7; tx++) {
                int xv = xx + 3 * (tx - 3); if (xv < 0 || xv >= 32) continue;
                acc += ws[(tz * 7 + ty) * 7 + tx] * ib[(zz * 32 + yy) * 32 + xv];
            }
        }
    }
    out[((size_t)b * CCH + c) * SVOL + s] = acc;
}

// ---------------- offset conv 3x3x3: 48 -> 81 ----------------
__global__ __launch_bounds__(256)
void offconv_kernel(const float* __restrict__ a1, const float* __restrict__ w,
                    const float* __restrict__ bias, float* __restrict__ off) {
    __shared__ float ws[CCH * 81];  // ws[ci*81+o]
    int tid = threadIdx.x;
    int s = blockIdx.x * 256 + tid; int b = blockIdx.y;
    int z = s >> 10, y = (s >> 5) & 31, xx = s & 31;
    const float* ib = a1 + (size_t)b * CCH * SVOL;
    float acc[81];
    #pragma unroll
    for (int o = 0; o < 81; o++) acc[o] = bias[o];
    for (int tap = 0; tap < 27; tap++) {
        __syncthreads();
        for (int i = tid; i < CCH * 81; i += 256) {
            int o = i / CCH, ci = i % CCH;
            ws[ci * 81 + o] = w[(o * CCH + ci) * 27 + tap];
        }
        __syncthreads();
        int dz = tap / 9 - 1, dy = (tap / 3) % 3 - 1, dx = tap % 3 - 1;
        int zz = z + dz, yy = y + dy, xv = xx + dx;
        bool ok = (zz >= 0 && zz < 32 && yy >= 0 && yy < 32 && xv >= 0 && xv < 32);
        if (ok) {
            int si = (zz * 32 + yy) * 32 + xv;
            for (int ci = 0; ci < CCH; ci++) {
                float v = ib[ci * SVOL + si];
                #pragma unroll
                for (int o = 0; o < 81; o++) acc[o] += ws[ci * 81 + o] * v;
            }
        }
    }
    float* ob = off + (size_t)b * 81 * SVOL + s;
    #pragma unroll
    for (int o = 0; o < 81; o++) ob[o * SVOL] = acc[o];
}

// ---------------- deformable conv 3x3x3 ----------------
__global__ __launch_bounds__(256)
void deform_kernel(const float* __restrict__ a1, const float* __restrict__ off,
                   const float* __restrict__ dcw, const float* __restrict__ dcb,
                   float* __restrict__ out) {
    __shared__ float ws[CCH * CCH];  // ws[ci*48+o]
    int tid = threadIdx.x;
    int s = blockIdx.x * 256 + tid; int b = blockIdx.y;
    int z = s >> 10, y = (s >> 5) & 31, xx = s & 31;
    const float* ib = a1 + (size_t)b * CCH * SVOL;
    const float* ob = off + (size_t)b * 81 * SVOL + s;
    float acc[CCH];
    #pragma unroll
    for (int o = 0; o < CCH; o++) acc[o] = dcb[o];
    for (int k = 0; k < 27; k++) {
        __syncthreads();
        for (int i = tid; i < CCH * CCH; i += 256) {
            int o = i / CCH, ci = i % CCH;
            ws[ci * CCH + o] = dcw[(o * CCH + ci) * 27 + k];
        }
        __syncthreads();
        int kd = k / 9 - 1, kh = (k / 3) % 3 - 1, kw = k % 3 - 1;
        float zf = (float)z + (float)kd + ob[(k * 3 + 0) * SVOL];
        float yf = (float)y + (float)kh + ob[(k * 3 + 1) * SVOL];
        float xf = (float)xx + (float)kw + ob[(k * 3 + 2) * SVOL];
        float z0 = floorf(zf), y0 = floorf(yf), x0 = floorf(xf);
        float tz = zf - z0, ty = yf - y0, tx = xf - x0;
        int iz0 = (int)z0, iy0 = (int)y0, ix0 = (int)x0;
        float cw[8]; int cidx[8];
        #pragma unroll
        for (int corner = 0; corner < 8; corner++) {
            int dz = corner >> 2, dy = (corner >> 1) & 1, dx = corner & 1;
            int zi = iz0 + dz, yi = iy0 + dy, xi = ix0 + dx;
            bool valid = (zi >= 0 && zi < 32 && yi >= 0 && yi < 32 && xi >= 0 && xi < 32);
            float wgt = (dz ? tz : 1.f - tz) * (dy ? ty : 1.f - ty) * (dx ? tx : 1.f - tx);
            cw[corner] = valid ? wgt : 0.f;
            int zc = min(max(zi, 0), 31), yc = min(max(yi, 0), 31), xc = min(max(xi, 0), 31);
            cidx[corner] = (zc * 32 + yc) * 32 + xc;
        }
        for (int ci = 0; ci < CCH; ci++) {
            const float* p = ib + ci * SVOL;
            float val = 0.f;
            #pragma unroll
            for (int corner = 0; corner < 8; corner++) val += cw[corner] * p[cidx[corner]];
            #pragma unroll
            for (int o = 0; o < CCH; o++) acc[o] += ws[ci * CCH + o] * val;
        }
    }
    float* op = out + (size_t)b * CCH * SVOL + s;
    #pragma unroll
    for (int o = 0; o < CCH; o++) op[o * SVOL] = acc[o];
}

// ---------------- fused: c1(1x1x1) -> gate(*u) -> p2(1x1x1) -> +shortcut -> skip ----------------
__global__ __launch_bounds__(256)
void gate_kernel(const float* __restrict__ dc, const float* __restrict__ u,
                 const float* __restrict__ xn, const float* __restrict__ x,
                 const float* __restrict__ c1w, const float* __restrict__ c1b,
                 const float* __restrict__ p2w, const float* __restrict__ p2b,
                 const float* __restrict__ gamma, float* __restrict__ skip) {
    __shared__ float w1[CCH * CCH];
    __shared__ float w2[CCH * CCH];
    __shared__ float b1s[CCH], b2s[CCH], gs[CCH];
    int tid = threadIdx.x;
    for (int i = tid; i < CCH * CCH; i += 256) {
        int o = i / CCH, ci = i % CCH;
        w1[ci * CCH + o] = c1w[o * CCH + ci];
        w2[ci * CCH + o] = p2w[o * CCH + ci];
    }
    if (tid < CCH) { b1s[tid] = c1b[tid]; b2s[tid] = p2b[tid]; gs[tid] = gamma[tid]; }
    __syncthreads();
    int s = blockIdx.x * 256 + tid; int b = blockIdx.y;
    size_t base = (size_t)b * CCH * SVOL + s;
    float a2[CCH];
    #pragma unroll
    for (int o = 0; o < CCH; o++) a2[o] = b1s[o];
    for (int ci = 0; ci < CCH; ci++) {
        float v = dc[base + ci * SVOL];
        #pragma unroll
        for (int o = 0; o < CCH; o++) a2[o] += w1[ci * CCH + o] * v;
    }
    #pragma unroll
    for (int o = 0; o < CCH; o++) a2[o] *= u[base + o * SVOL];
    float v3[CCH];
    #pragma unroll
    for (int o = 0; o < CCH; o++) v3[o] = b2s[o];
    for (int ci = 0; ci < CCH; ci++) {
        float v = a2[ci];
        #pragma unroll
        for (int o = 0; o < CCH; o++) v3[o] += w2[ci * CCH + o] * v;
    }
    #pragma unroll
    for (int o = 0; o < CCH; o++) {
        float vv = v3[o] + xn[base + o * SVOL];           // proj_2 + shortcut
        skip[base + o * SVOL] = x[base + o * SVOL] + gs[o] * vv;  // tok + gamma*epa
    }
}

// ---------------- u1: 3x3x3 conv (no bias) + BN1 + LeakyReLU ----------------
__global__ __launch_bounds__(256)
void u1_kernel(const float* __restrict__ in, const float* __restrict__ w,
               const float* __restrict__ bs, const float* __restrict__ bb,
               const float* __restrict__ bm, const float* __restrict__ bv,
               float* __restrict__ out) {
    __shared__ float ws[CCH * CCH];
    int tid = threadIdx.x;
    int s = blockIdx.x * 256 + tid; int b = blockIdx.y;
    int z = s >> 10, y = (s >> 5) & 31, xx = s & 31;
    const float* ib = in + (size_t)b * CCH * SVOL;
    float acc[CCH];
    #pragma unroll
    for (int o = 0; o < CCH; o++) acc[o] = 0.f;
    for (int tap = 0; tap < 27; tap++) {
        __syncthreads();
        for (int i = tid; i < CCH * CCH; i += 256) {
            int o = i / CCH, ci = i % CCH;
            ws[ci * CCH + o] = w[(o * CCH + ci) * 27 + tap];
        }
        __syncthreads();
        int dz = tap / 9 - 1, dy = (tap / 3) % 3 - 1, dx = tap % 3 - 1;
        int zz = z + dz, yy = y + dy, xv = xx + dx;
        bool ok = (zz >= 0 && zz < 32 && yy >= 0 && yy < 32 && xv >= 0 && xv < 32);
        if (ok) {
            int si = (zz * 32 + yy) * 32 + xv;
            for (int ci = 0; ci < CCH; ci++) {
                float v = ib[ci * SVOL + si];
                #pragma unroll
                for (int o = 0; o < CCH; o++) acc[o] += ws[ci * CCH + o] * v;
            }
        }
    }
    float* op = out + (size_t)b * CCH * SVOL + s;
    #pragma unroll
    for (int o = 0; o < CCH; o++) {
        float inv = rsqrtf(bv[o] + 1e-5f);
        float h = (acc[o] - bm[o]) * (bs[o] * inv) + bb[o];
        op[o * SVOL] = h >= 0.f ? h : 0.01f * h;
    }
}

// ---------------- u2: 3x3x3 conv + BN2 + (+skip) + LeakyReLU + pr(1x1x1) + residual ----------------
__global__ __launch_bounds__(256)
void u2_final_kernel(const float* __restrict__ h1, const float* __restrict__ skip,
                     const float* __restrict__ w,
                     const float* __restrict__ bs, const float* __restrict__ bb,
                     const float* __restrict__ bm, const float* __restrict__ bv,
                     const float* __restrict__ prw, const float* __restrict__ prb,
                     float* __restrict__ out) {
    __shared__ float ws[CCH * CCH];
    __shared__ float pw[CCH * CCH];
    int tid = threadIdx.x;
    for (int i = tid; i < CCH * CCH; i += 256) {
        int o = i / CCH, ci = i % CCH;
        pw[ci * CCH + o] = prw[o * CCH + ci];
    }
    int s = blockIdx.x * 256 + tid; int b = blockIdx.y;
    int z = s >> 10, y = (s >> 5) & 31, xx = s & 31;
    const float* ib = h1 + (size_t)b * CCH * SVOL;
    float acc[CCH];
    #pragma unroll
    for (int o = 0; o < CCH; o++) acc[o] = 0.f;
    for (int tap = 0; tap < 27; tap++) {
        __syncthreads();
        for (int i = tid; i < CCH * CCH; i += 256) {
            int o = i / CCH, ci = i % CCH;
            ws[ci * CCH + o] = w[(o * CCH + ci) * 27 + tap];
        }
        __syncthreads();
        int dz = tap / 9 - 1, dy = (tap / 3) % 3 - 1, dx = tap % 3 - 1;
        int zz = z + dz, yy = y + dy, xv = xx + dx;
        bool ok = (zz >= 0 && zz < 32 && yy >= 0 && yy < 32 && xv >= 0 && xv < 32);
        if (ok) {
            int si = (zz * 32 + yy) * 32 + xv;
            for (int ci = 0; ci < CCH; ci++) {
                float v = ib[ci * SVOL + si];
                #pragma unroll
                for (int o = 0; o < CCH; o++) acc[o] += ws[ci * CCH + o] * v;
            }
        }
    }
    size_t base = (size_t)b * CCH * SVOL + s;
    // BN2 + skip + leaky -> attn (reuse acc)
    #pragma unroll
    for (int o = 0; o < CCH; o++) {
        float inv = rsqrtf(bv[o] + 1e-5f);
        float h = (acc[o] - bm[o]) * (bs[o] * inv) + bb[o];
        float a = h + skip[base + o * SVOL];
        acc[o] = a >= 0.f ? a : 0.01f * a;
    }
    float res[CCH];
    #pragma unroll
    for (int o = 0; o < CCH; o++) res[o] = prb[o];
    for (int ci = 0; ci < CCH; ci++) {
        float v = acc[ci];
        #pragma unroll
        for (int o = 0; o < CCH; o++) res[o] += pw[ci * CCH + o] * v;
    }
    #pragma unroll
    for (int o = 0; o < CCH; o++) out[base + o * SVOL] = skip[base + o * SVOL] + res[o];
}

extern "C" void kernel_launch(void* const* d_in, const int* in_sizes, int n_in,
                              void* d_out, int out_size, void* d_ws, size_t ws_size,
                              hipStream_t stream) {
    (void)in_sizes; (void)n_in; (void)out_size; (void)ws_size;
    const float* x     = (const float*)d_in[0];
    const float* ln_s  = (const float*)d_in[1];
    const float* ln_b  = (const float*)d_in[2];
    const float* gamma = (const float*)d_in[3];
    const float* p1_w  = (const float*)d_in[4];
    const float* p1_b  = (const float*)d_in[5];
    const float* p2_w  = (const float*)d_in[6];
    const float* p2_b  = (const float*)d_in[7];
    const float* c0_w  = (const float*)d_in[8];
    const float* c0_b  = (const float*)d_in[9];
    const float* cs_w  = (const float*)d_in[10];
    const float* cs_b  = (const float*)d_in[11];
    const float* off_w = (const float*)d_in[12];
    const float* off_b = (const float*)d_in[13];
    const float* dc_w  = (const float*)d_in[14];
    const float* dc_b  = (const float*)d_in[15];
    const float* c1_w  = (const float*)d_in[16];
    const float* c1_b  = (const float*)d_in[17];
    const float* u1_w  = (const float*)d_in[18];
    const float* bn1_s = (const float*)d_in[19];
    const float* bn1_b = (const float*)d_in[20];
    const float* bn1_m = (const float*)d_in[21];
    const float* bn1_v = (const float*)d_in[22];
    const float* u2_w  = (const float*)d_in[23];
    const float* bn2_s = (const float*)d_in[24];
    const float* bn2_b = (const float*)d_in[25];
    const float* bn2_m = (const float*)d_in[26];
    const float* bn2_v = (const float*)d_in[27];
    const float* pr_w  = (const float*)d_in[28];
    const float* pr_b  = (const float*)d_in[29];
    float* out = (float*)d_out;

    float* wsf = (float*)d_ws;
    const size_t TS = (size_t)NB * CCH * SVOL;   // 3,145,728 floats
    float* xn   = out;            // reuse d_out as xn scratch (dead before final write)
    float* ubuf = wsf;            // gelu output u, later h1
    float* bufA = wsf + TS;       // dw5 out, later deform out
    float* bufB = wsf + 2 * TS;   // dw7 out (a1), later skip
    float* offb = wsf + 3 * TS;   // offsets [B,81,S] = 5,308,416 floats
    // total ws use: 3*TS + B*81*S = 14,745,600 floats = 59.0 MB

    dim3 blk(256);
    dim3 gpos(SVOL / 256, NB);
    dim3 gdw(SVOL / 256, CCH, NB);

    hipLaunchKernelGGL(ln_kernel,       gpos, blk, 0, stream, x, ln_s, ln_b, xn);
    hipLaunchKernelGGL(p1_gelu_kernel,  gpos, blk, 0, stream, xn, p1_w, p1_b, ubuf);
    hipLaunchKernelGGL(dw5_kernel,      gdw,  blk, 0, stream, ubuf, c0_w, c0_b, bufA);
    hipLaunchKernelGGL(dw7_kernel,      gdw,  blk, 0, stream, bufA, cs_w, cs_b, bufB);
    hipLaunchKernelGGL(offconv_kernel,  gpos, blk, 0, stream, bufB, off_w, off_b, offb);
    hipLaunchKernelGGL(deform_kernel,   gpos, blk, 0, stream, bufB, offb, dc_w, dc_b, bufA);
    hipLaunchKernelGGL(gate_kernel,     gpos, blk, 0, stream, bufA, ubuf, xn, x,
                       c1_w, c1_b, p2_w, p2_b, gamma, bufB);
    hipLaunchKernelGGL(u1_kernel,       gpos, blk, 0, stream, bufB, u1_w,
                       bn1_s, bn1_b, bn1_m, bn1_v, ubuf);
    hipLaunchKernelGGL(u2_final_kernel, gpos, blk, 0, stream, ubuf, bufB, u2_w,
                       bn2_s, bn2_b, bn2_m, bn2_v, pr_w, pr_b, out);
}

// Round 3
// 2385.928 us; speedup vs baseline: 1.5926x; 1.4276x over previous
//
#include <hip/hip_runtime.h>
#include <math.h>

#define CCH 48
#define SDIM 32
#define SVOL (SDIM*SDIM*SDIM)
#define NB 2

// ---------------- LayerNorm over C ----------------
__global__ __launch_bounds__(256)
void ln_kernel(const float* __restrict__ x, const float* __restrict__ ln_s,
               const float* __restrict__ ln_b, float* __restrict__ xn) {
    int s = blockIdx.x * 256 + threadIdx.x;
    int b = blockIdx.y;
    const float* xb = x + (size_t)b * CCH * SVOL + s;
    float v[CCH];
    float mu = 0.f;
    #pragma unroll
    for (int c = 0; c < CCH; c++) { v[c] = xb[c * SVOL]; mu += v[c]; }
    mu *= (1.0f / CCH);
    float var = 0.f;
    #pragma unroll
    for (int c = 0; c < CCH; c++) { float d = v[c] - mu; var += d * d; }
    var *= (1.0f / CCH);
    float inv = rsqrtf(var + 1e-5f);
    float* o = xn + (size_t)b * CCH * SVOL + s;
    #pragma unroll
    for (int c = 0; c < CCH; c++) o[c * SVOL] = (v[c] - mu) * inv * ln_s[c] + ln_b[c];
}

// ---------------- 1x1x1 conv + exact GELU (2 groups x 24 outputs) ----------------
__global__ __launch_bounds__(256)
void p1_gelu_kernel(const float* __restrict__ xn, const float* __restrict__ w,
                    const float* __restrict__ bias, float* __restrict__ u) {
    __shared__ float ws[CCH * 24];   // ws[ci*24+o]
    int tid = threadIdx.x;
    int g = blockIdx.y;              // output group
    int b = blockIdx.z;
    for (int i = tid; i < CCH * 24; i += 256) {
        int o = i / CCH, ci = i % CCH;
        ws[ci * 24 + o] = w[(g * 24 + o) * CCH + ci];
    }
    __syncthreads();
    int s = blockIdx.x * 256 + tid;
    const float* xb = xn + (size_t)b * CCH * SVOL + s;
    float acc[24];
    #pragma unroll
    for (int o = 0; o < 24; o++) acc[o] = bias[g * 24 + o];
    for (int c = 0; c < CCH; c++) {
        float v = xb[c * SVOL];
        #pragma unroll
        for (int o = 0; o < 24; o++) acc[o] += ws[c * 24 + o] * v;
    }
    float* ub = u + (size_t)b * CCH * SVOL + s + (size_t)(g * 24) * SVOL;
    #pragma unroll
    for (int o = 0; o < 24; o++) {
        float a = acc[o];
        ub[o * SVOL] = 0.5f * a * (1.0f + erff(a * 0.70710678118654752f));
    }
}

// ---------------- depthwise 5x5x5 pad 2 ----------------
__global__ __launch_bounds__(256)
void dw5_kernel(const float* __restrict__ in, const float* __restrict__ w,
                const float* __restrict__ bias, float* __restrict__ out) {
    __shared__ float ws[125];
    int tid = threadIdx.x;
    int c = blockIdx.y, b = blockIdx.z;
    if (tid < 125) ws[tid] = w[c * 125 + tid];
    __syncthreads();
    int s = blockIdx.x * 256 + tid;
    int z = s >> 10, y = (s >> 5) & 31, xx = s & 31;
    const float* ib = in + ((size_t)b * CCH + c) * SVOL;
    float acc = bias[c];
    for (int dz = -2; dz <= 2; dz++) {
        int zz = z + dz; if (zz < 0 || zz >= 32) continue;
        for (int dy = -2; dy <= 2; dy++) {
            int yy = y + dy; if (yy < 0 || yy >= 32) continue;
            #pragma unroll
            for (int dx = -2; dx <= 2; dx++) {
                int xv = xx + dx; if (xv < 0 || xv >= 32) continue;
                acc += ws[((dz + 2) * 5 + (dy + 2)) * 5 + (dx + 2)] * ib[(zz * 32 + yy) * 32 + xv];
            }
        }
    }
    out[((size_t)b * CCH + c) * SVOL + s] = acc;
}

// ---------------- depthwise 7x7x7 dil 3 pad 9 ----------------
__global__ __launch_bounds__(256)
void dw7_kernel(const float* __restrict__ in, const float* __restrict__ w,
                const float* __restrict__ bias, float* __restrict__ out) {
    __shared__ float ws[343];
    int tid = threadIdx.x;
    int c = blockIdx.y, b = blockIdx.z;
    for (int i = tid; i < 343; i += 256) ws[i] = w[c * 343 + i];
    __syncthreads();
    int s = blockIdx.x * 256 + tid;
    int z = s >> 10, y = (s >> 5) & 31, xx = s & 31;
    const float* ib = in + ((size_t)b * CCH + c) * SVOL;
    float acc = bias[c];
    for (int tz = 0; tz < 7; tz++) {
        int zz = z + 3 * (tz - 3); if (zz < 0 || zz >= 32) continue;
        for (int ty = 0; ty < 7; ty++) {
            int yy = y + 3 * (ty - 3); if (yy < 0 || yy >= 32) continue;
            #pragma unroll
            for (int tx = 0; tx < 7; tx++) {
                int xv = xx + 3 * (tx - 3); if (xv < 0 || xv >= 32) continue;
                acc += ws[(tz * 7 + ty) * 7 + tx] * ib[(zz * 32 + yy) * 32 + xv];
            }
        }
    }
    out[((size_t)b * CCH + c) * SVOL + s] = acc;
}

// ---------------- offset conv 3x3x3: 48 -> 81 (3 groups x 27 outputs) ----------------
__global__ __launch_bounds__(256)
void offconv_kernel(const float* __restrict__ a1, const float* __restrict__ w,
                    const float* __restrict__ bias, float* __restrict__ off) {
    __shared__ float ws[CCH * 27];  // ws[ci*27+o]
    int tid = threadIdx.x;
    int g = blockIdx.y;             // 0..2
    int b = blockIdx.z;
    int s = blockIdx.x * 256 + tid;
    int z = s >> 10, y = (s >> 5) & 31, xx = s & 31;
    const float* ib = a1 + (size_t)b * CCH * SVOL;
    float acc[27];
    #pragma unroll
    for (int o = 0; o < 27; o++) acc[o] = bias[g * 27 + o];
    for (int tap = 0; tap < 27; tap++) {
        __syncthreads();
        for (int i = tid; i < CCH * 27; i += 256) {
            int o = i / CCH, ci = i % CCH;
            ws[ci * 27 + o] = w[((g * 27 + o) * CCH + ci) * 27 + tap];
        }
        __syncthreads();
        int dz = tap / 9 - 1, dy = (tap / 3) % 3 - 1, dx = tap % 3 - 1;
        int zz = z + dz, yy = y + dy, xv = xx + dx;
        bool ok = (zz >= 0 && zz < 32 && yy >= 0 && yy < 32 && xv >= 0 && xv < 32);
        if (ok) {
            int si = (zz * 32 + yy) * 32 + xv;
            for (int ci = 0; ci < CCH; ci++) {
                float v = ib[ci * SVOL + si];
                #pragma unroll
                for (int o = 0; o < 27; o++) acc[o] += ws[ci * 27 + o] * v;
            }
        }
    }
    float* ob = off + (size_t)b * 81 * SVOL + (size_t)(g * 27) * SVOL + s;
    #pragma unroll
    for (int o = 0; o < 27; o++) ob[o * SVOL] = acc[o];
}

// ---------------- deformable conv 3x3x3 (2 groups x 24 outputs) ----------------
__global__ __launch_bounds__(256)
void deform_kernel(const float* __restrict__ a1, const float* __restrict__ off,
                   const float* __restrict__ dcw, const float* __restrict__ dcb,
                   float* __restrict__ out) {
    __shared__ float ws[CCH * 24];  // ws[ci*24+o]
    int tid = threadIdx.x;
    int g = blockIdx.y;             // 0..1
    int b = blockIdx.z;
    int s = blockIdx.x * 256 + tid;
    int z = s >> 10, y = (s >> 5) & 31, xx = s & 31;
    const float* ib = a1 + (size_t)b * CCH * SVOL;
    const float* ob = off + (size_t)b * 81 * SVOL + s;
    float acc[24];
    #pragma unroll
    for (int o = 0; o < 24; o++) acc[o] = dcb[g * 24 + o];
    for (int k = 0; k < 27; k++) {
        __syncthreads();
        for (int i = tid; i < CCH * 24; i += 256) {
            int o = i / CCH, ci = i % CCH;
            ws[ci * 24 + o] = dcw[((g * 24 + o) * CCH + ci) * 27 + k];
        }
        __syncthreads();
        int kd = k / 9 - 1, kh = (k / 3) % 3 - 1, kw = k % 3 - 1;
        float zf = (float)z + (float)kd + ob[(k * 3 + 0) * SVOL];
        float yf = (float)y + (float)kh + ob[(k * 3 + 1) * SVOL];
        float xf = (float)xx + (float)kw + ob[(k * 3 + 2) * SVOL];
        float z0 = floorf(zf), y0 = floorf(yf), x0 = floorf(xf);
        float tz = zf - z0, ty = yf - y0, tx = xf - x0;
        int iz0 = (int)z0, iy0 = (int)y0, ix0 = (int)x0;
        float cw[8]; int cidx[8];
        #pragma unroll
        for (int corner = 0; corner < 8; corner++) {
            int dz = corner >> 2, dy = (corner >> 1) & 1, dx = corner & 1;
            int zi = iz0 + dz, yi = iy0 + dy, xi = ix0 + dx;
            bool valid = (zi >= 0 && zi < 32 && yi >= 0 && yi < 32 && xi >= 0 && xi < 32);
            float wgt = (dz ? tz : 1.f - tz) * (dy ? ty : 1.f - ty) * (dx ? tx : 1.f - tx);
            cw[corner] = valid ? wgt : 0.f;
            int zc = min(max(zi, 0), 31), yc = min(max(yi, 0), 31), xc = min(max(xi, 0), 31);
            cidx[corner] = (zc * 32 + yc) * 32 + xc;
        }
        for (int ci = 0; ci < CCH; ci++) {
            const float* p = ib + ci * SVOL;
            float val = 0.f;
            #pragma unroll
            for (int corner = 0; corner < 8; corner++) val += cw[corner] * p[cidx[corner]];
            #pragma unroll
            for (int o = 0; o < 24; o++) acc[o] += ws[ci * 24 + o] * val;
        }
    }
    float* op = out + (size_t)b * CCH * SVOL + (size_t)(g * 24) * SVOL + s;
    #pragma unroll
    for (int o = 0; o < 24; o++) op[o * SVOL] = acc[o];
}

// ---------------- gate1: a2 = (c1 . dc + c1b) * u   (2 groups x 24) ----------------
__global__ __launch_bounds__(256)
void gate1_kernel(const float* __restrict__ dc, const float* __restrict__ u,
                  const float* __restrict__ c1w, const float* __restrict__ c1b,
                  float* __restrict__ a2buf) {
    __shared__ float w1[CCH * 24];
    int tid = threadIdx.x;
    int g = blockIdx.y, b = blockIdx.z;
    for (int i = tid; i < CCH * 24; i += 256) {
        int o = i / CCH, ci = i % CCH;
        w1[ci * 24 + o] = c1w[(g * 24 + o) * CCH + ci];
    }
    __syncthreads();
    int s = blockIdx.x * 256 + tid;
    size_t base = (size_t)b * CCH * SVOL + s;
    float acc[24];
    #pragma unroll
    for (int o = 0; o < 24; o++) acc[o] = c1b[g * 24 + o];
    for (int ci = 0; ci < CCH; ci++) {
        float v = dc[base + ci * SVOL];
        #pragma unroll
        for (int o = 0; o < 24; o++) acc[o] += w1[ci * 24 + o] * v;
    }
    #pragma unroll
    for (int o = 0; o < 24; o++)
        a2buf[base + (size_t)(g * 24 + o) * SVOL] = acc[o] * u[base + (size_t)(g * 24 + o) * SVOL];
}

// ---------------- gate2: skip = x + gamma*(p2 . a2 + p2b + xn)  (2 groups x 24) ----------------
__global__ __launch_bounds__(256)
void gate2_kernel(const float* __restrict__ a2buf, const float* __restrict__ xn,
                  const float* __restrict__ x,
                  const float* __restrict__ p2w, const float* __restrict__ p2b,
                  const float* __restrict__ gamma, float* __restrict__ skip) {
    __shared__ float w2[CCH * 24];
    int tid = threadIdx.x;
    int g = blockIdx.y, b = blockIdx.z;
    for (int i = tid; i < CCH * 24; i += 256) {
        int o = i / CCH, ci = i % CCH;
        w2[ci * 24 + o] = p2w[(g * 24 + o) * CCH + ci];
    }
    __syncthreads();
    int s = blockIdx.x * 256 + tid;
    size_t base = (size_t)b * CCH * SVOL + s;
    float acc[24];
    #pragma unroll
    for (int o = 0; o < 24; o++) acc[o] = p2b[g * 24 + o];
    for (int ci = 0; ci < CCH; ci++) {
        float v = a2buf[base + ci * SVOL];
        #pragma unroll
        for (int o = 0; o < 24; o++) acc[o] += w2[ci * 24 + o] * v;
    }
    #pragma unroll
    for (int o = 0; o < 24; o++) {
        int oc = g * 24 + o;
        float vv = acc[o] + xn[base + (size_t)oc * SVOL];
        skip[base + (size_t)oc * SVOL] = x[base + (size_t)oc * SVOL] + gamma[oc] * vv;
    }
}

// ---------------- u1: 3x3x3 conv + BN1 + LeakyReLU (2 groups x 24) ----------------
__global__ __launch_bounds__(256)
void u1_kernel(const float* __restrict__ in, const float* __restrict__ w,
               const float* __restrict__ bs, const float* __restrict__ bb,
               const float* __restrict__ bm, const float* __restrict__ bv,
               float* __restrict__ out) {
    __shared__ float ws[CCH * 24];
    int tid = threadIdx.x;
    int g = blockIdx.y, b = blockIdx.z;
    int s = blockIdx.x * 256 + tid;
    int z = s >> 10, y = (s >> 5) & 31, xx = s & 31;
    const float* ib = in + (size_t)b * CCH * SVOL;
    float acc[24];
    #pragma unroll
    for (int o = 0; o < 24; o++) acc[o] = 0.f;
    for (int tap = 0; tap < 27; tap++) {
        __syncthreads();
        for (int i = tid; i < CCH * 24; i += 256) {
            int o = i / CCH, ci = i % CCH;
            ws[ci * 24 + o] = w[((g * 24 + o) * CCH + ci) * 27 + tap];
        }
        __syncthreads();
        int dz = tap / 9 - 1, dy = (tap / 3) % 3 - 1, dx = tap % 3 - 1;
        int zz = z + dz, yy = y + dy, xv = xx + dx;
        bool ok = (zz >= 0 && zz < 32 && yy >= 0 && yy < 32 && xv >= 0 && xv < 32);
        if (ok) {
            int si = (zz * 32 + yy) * 32 + xv;
            for (int ci = 0; ci < CCH; ci++) {
                float v = ib[ci * SVOL + si];
                #pragma unroll
                for (int o = 0; o < 24; o++) acc[o] += ws[ci * 24 + o] * v;
            }
        }
    }
    float* op = out + (size_t)b * CCH * SVOL + (size_t)(g * 24) * SVOL + s;
    #pragma unroll
    for (int o = 0; o < 24; o++) {
        int oc = g * 24 + o;
        float inv = rsqrtf(bv[oc] + 1e-5f);
        float h = (acc[o] - bm[oc]) * (bs[oc] * inv) + bb[oc];
        op[o * SVOL] = h >= 0.f ? h : 0.01f * h;
    }
}

// ---------------- u2_bn: 3x3x3 conv + BN2 + (+skip) + LeakyReLU -> attn (2 groups x 24) ----------------
__global__ __launch_bounds__(256)
void u2_bn_kernel(const float* __restrict__ h1, const float* __restrict__ skip,
                  const float* __restrict__ w,
                  const float* __restrict__ bs, const float* __restrict__ bb,
                  const float* __restrict__ bm, const float* __restrict__ bv,
                  float* __restrict__ attn) {
    __shared__ float ws[CCH * 24];
    int tid = threadIdx.x;
    int g = blockIdx.y, b = blockIdx.z;
    int s = blockIdx.x * 256 + tid;
    int z = s >> 10, y = (s >> 5) & 31, xx = s & 31;
    const float* ib = h1 + (size_t)b * CCH * SVOL;
    float acc[24];
    #pragma unroll
    for (int o = 0; o < 24; o++) acc[o] = 0.f;
    for (int tap = 0; tap < 27; tap++) {
        __syncthreads();
        for (int i = tid; i < CCH * 24; i += 256) {
            int o = i / CCH, ci = i % CCH;
            ws[ci * 24 + o] = w[((g * 24 + o) * CCH + ci) * 27 + tap];
        }
        __syncthreads();
        int dz = tap / 9 - 1, dy = (tap / 3) % 3 - 1, dx = tap % 3 - 1;
        int zz = z + dz, yy = y + dy, xv = xx + dx;
        bool ok = (zz >= 0 && zz < 32 && yy >= 0 && yy < 32 && xv >= 0 && xv < 32);
        if (ok) {
            int si = (zz * 32 + yy) * 32 + xv;
            for (int ci = 0; ci < CCH; ci++) {
                float v = ib[ci * SVOL + si];
                #pragma unroll
                for (int o = 0; o < 24; o++) acc[o] += ws[ci * 24 + o] * v;
            }
        }
    }
    size_t base = (size_t)b * CCH * SVOL + s;
    #pragma unroll
    for (int o = 0; o < 24; o++) {
        int oc = g * 24 + o;
        float inv = rsqrtf(bv[oc] + 1e-5f);
        float h = (acc[o] - bm[oc]) * (bs[oc] * inv) + bb[oc];
        float a = h + skip[base + (size_t)oc * SVOL];
        attn[base + (size_t)oc * SVOL] = a >= 0.f ? a : 0.01f * a;
    }
}

// ---------------- pr_final: out = skip + pr(attn)  (2 groups x 24) ----------------
__global__ __launch_bounds__(256)
void pr_final_kernel(const float* __restrict__ attn, const float* __restrict__ skip,
                     const float* __restrict__ prw, const float* __restrict__ prb,
                     float* __restrict__ out) {
    __shared__ float pw[CCH * 24];
    int tid = threadIdx.x;
    int g = blockIdx.y, b = blockIdx.z;
    for (int i = tid; i < CCH * 24; i += 256) {
        int o = i / CCH, ci = i % CCH;
        pw[ci * 24 + o] = prw[(g * 24 + o) * CCH + ci];
    }
    __syncthreads();
    int s = blockIdx.x * 256 + tid;
    size_t base = (size_t)b * CCH * SVOL + s;
    float acc[24];
    #pragma unroll
    for (int o = 0; o < 24; o++) acc[o] = prb[g * 24 + o];
    for (int ci = 0; ci < CCH; ci++) {
        float v = attn[base + ci * SVOL];
        #pragma unroll
        for (int o = 0; o < 24; o++) acc[o] += pw[ci * 24 + o] * v;
    }
    #pragma unroll
    for (int o = 0; o < 24; o++) {
        int oc = g * 24 + o;
        out[base + (size_t)oc * SVOL] = skip[base + (size_t)oc * SVOL] + acc[o];
    }
}

extern "C" void kernel_launch(void* const* d_in, const int* in_sizes, int n_in,
                              void* d_out, int out_size, void* d_ws, size_t ws_size,
                              hipStream_t stream) {
    (void)in_sizes; (void)n_in; (void)out_size; (void)ws_size;
    const float* x     = (const float*)d_in[0];
    const float* ln_s  = (const float*)d_in[1];
    const float* ln_b  = (const float*)d_in[2];
    const float* gamma = (const float*)d_in[3];
    const float* p1_w  = (const float*)d_in[4];
    const float* p1_b  = (const float*)d_in[5];
    const float* p2_w  = (const float*)d_in[6];
    const float* p2_b  = (const float*)d_in[7];
    const float* c0_w  = (const float*)d_in[8];
    const float* c0_b  = (const float*)d_in[9];
    const float* cs_w  = (const float*)d_in[10];
    const float* cs_b  = (const float*)d_in[11];
    const float* off_w = (const float*)d_in[12];
    const float* off_b = (const float*)d_in[13];
    const float* dc_w  = (const float*)d_in[14];
    const float* dc_b  = (const float*)d_in[15];
    const float* c1_w  = (const float*)d_in[16];
    const float* c1_b  = (const float*)d_in[17];
    const float* u1_w  = (const float*)d_in[18];
    const float* bn1_s = (const float*)d_in[19];
    const float* bn1_b = (const float*)d_in[20];
    const float* bn1_m = (const float*)d_in[21];
    const float* bn1_v = (const float*)d_in[22];
    const float* u2_w  = (const float*)d_in[23];
    const float* bn2_s = (const float*)d_in[24];
    const float* bn2_b = (const float*)d_in[25];
    const float* bn2_m = (const float*)d_in[26];
    const float* bn2_v = (const float*)d_in[27];
    const float* pr_w  = (const float*)d_in[28];
    const float* pr_b  = (const float*)d_in[29];
    float* out = (float*)d_out;

    float* wsf = (float*)d_ws;
    const size_t TS = (size_t)NB * CCH * SVOL;   // 3,145,728 floats
    float* xn   = out;            // d_out doubles as xn (dead before final write)
    float* ubuf = wsf;            // u (gelu out), later h1 (u1 out)
    float* bufA = wsf + TS;       // dw5 out -> deform out -> attn
    float* bufB = wsf + 2 * TS;   // dw7 out (a1) -> skip
    float* offb = wsf + 3 * TS;   // offsets [B,81,S]; later a2 (TS <= 5.3M floats)
    // ws use: 3*TS + NB*81*SVOL = 14,745,600 floats = 59.0 MB

    dim3 blk(256);
    dim3 gpos(SVOL / 256, NB);
    dim3 g2(SVOL / 256, 2, NB);
    dim3 g3(SVOL / 256, 3, NB);
    dim3 gdw(SVOL / 256, CCH, NB);

    hipLaunchKernelGGL(ln_kernel,       gpos, blk, 0, stream, x, ln_s, ln_b, xn);
    hipLaunchKernelGGL(p1_gelu_kernel,  g2,   blk, 0, stream, xn, p1_w, p1_b, ubuf);
    hipLaunchKernelGGL(dw5_kernel,      gdw,  blk, 0, stream, ubuf, c0_w, c0_b, bufA);
    hipLaunchKernelGGL(dw7_kernel,      gdw,  blk, 0, stream, bufA, cs_w, cs_b, bufB);
    hipLaunchKernelGGL(offconv_kernel,  g3,   blk, 0, stream, bufB, off_w, off_b, offb);
    hipLaunchKernelGGL(deform_kernel,   g2,   blk, 0, stream, bufB, offb, dc_w, dc_b, bufA);
    hipLaunchKernelGGL(gate1_kernel,    g2,   blk, 0, stream, bufA, ubuf, c1_w, c1_b, offb);
    hipLaunchKernelGGL(gate2_kernel,    g2,   blk, 0, stream, offb, xn, x, p2_w, p2_b, gamma, bufB);
    hipLaunchKernelGGL(u1_kernel,       g2,   blk, 0, stream, bufB, u1_w,
                       bn1_s, bn1_b, bn1_m, bn1_v, ubuf);
    hipLaunchKernelGGL(u2_bn_kernel,    g2,   blk, 0, stream, ubuf, bufB, u2_w,
                       bn2_s, bn2_b, bn2_m, bn2_v, bufA);
    hipLaunchKernelGGL(pr_final_kernel, g2,   blk, 0, stream, bufA, bufB, pr_w, pr_b, out);
}

// Round 4
// 2312.828 us; speedup vs baseline: 1.6430x; 1.0316x over previous
//
#include <hip/hip_runtime.h>
#include <math.h>

#define CCH 48
#define SDIM 32
#define SVOL (SDIM*SDIM*SDIM)
#define NB 2

// ---------------- LayerNorm over C ----------------
__global__ __launch_bounds__(256)
void ln_kernel(const float* __restrict__ x, const float* __restrict__ ln_s,
               const float* __restrict__ ln_b, float* __restrict__ xn) {
    int s = blockIdx.x * 256 + threadIdx.x;
    int b = blockIdx.y;
    const float* xb = x + (size_t)b * CCH * SVOL + s;
    float v[CCH];
    float mu = 0.f;
    #pragma unroll
    for (int c = 0; c < CCH; c++) { v[c] = xb[c * SVOL]; mu += v[c]; }
    mu *= (1.0f / CCH);
    float var = 0.f;
    #pragma unroll
    for (int c = 0; c < CCH; c++) { float d = v[c] - mu; var += d * d; }
    var *= (1.0f / CCH);
    float inv = rsqrtf(var + 1e-5f);
    float* o = xn + (size_t)b * CCH * SVOL + s;
    #pragma unroll
    for (int c = 0; c < CCH; c++) o[c * SVOL] = (v[c] - mu) * inv * ln_s[c] + ln_b[c];
}

// ---------------- 1x1x1 conv + exact GELU (4 groups x 12 outputs) ----------------
__global__ __launch_bounds__(256, 4)
void p1_gelu_kernel(const float* __restrict__ xn, const float* __restrict__ w,
                    const float* __restrict__ bias, float* __restrict__ u) {
    __shared__ float ws[CCH * 12];   // ws[ci*12+o]
    int tid = threadIdx.x;
    int g = blockIdx.y;              // output group 0..3
    int b = blockIdx.z;
    for (int i = tid; i < CCH * 12; i += 256) {
        int o = i % 12, ci = i / 12;
        ws[ci * 12 + o] = w[(g * 12 + o) * CCH + ci];
    }
    __syncthreads();
    int s = blockIdx.x * 256 + tid;
    const float* xb = xn + (size_t)b * CCH * SVOL + s;
    float acc[12];
    #pragma unroll
    for (int o = 0; o < 12; o++) acc[o] = bias[g * 12 + o];
    for (int c = 0; c < CCH; c++) {
        float v = xb[c * SVOL];
        #pragma unroll
        for (int o = 0; o < 12; o++) acc[o] += ws[c * 12 + o] * v;
    }
    float* ub = u + (size_t)b * CCH * SVOL + s + (size_t)(g * 12) * SVOL;
    #pragma unroll
    for (int o = 0; o < 12; o++) {
        float a = acc[o];
        ub[o * SVOL] = 0.5f * a * (1.0f + erff(a * 0.70710678118654752f));
    }
}

// ---------------- depthwise 5x5x5 pad 2 ----------------
__global__ __launch_bounds__(256)
void dw5_kernel(const float* __restrict__ in, const float* __restrict__ w,
                const float* __restrict__ bias, float* __restrict__ out) {
    __shared__ float ws[125];
    int tid = threadIdx.x;
    int c = blockIdx.y, b = blockIdx.z;
    if (tid < 125) ws[tid] = w[c * 125 + tid];
    __syncthreads();
    int s = blockIdx.x * 256 + tid;
    int z = s >> 10, y = (s >> 5) & 31, xx = s & 31;
    const float* ib = in + ((size_t)b * CCH + c) * SVOL;
    float acc = bias[c];
    for (int dz = -2; dz <= 2; dz++) {
        int zz = z + dz; if (zz < 0 || zz >= 32) continue;
        for (int dy = -2; dy <= 2; dy++) {
            int yy = y + dy; if (yy < 0 || yy >= 32) continue;
            #pragma unroll
            for (int dx = -2; dx <= 2; dx++) {
                int xv = xx + dx; if (xv < 0 || xv >= 32) continue;
                acc += ws[((dz + 2) * 5 + (dy + 2)) * 5 + (dx + 2)] * ib[(zz * 32 + yy) * 32 + xv];
            }
        }
    }
    out[((size_t)b * CCH + c) * SVOL + s] = acc;
}

// ---------------- depthwise 7x7x7 dil 3 pad 9 ----------------
__global__ __launch_bounds__(256)
void dw7_kernel(const float* __restrict__ in, const float* __restrict__ w,
                const float* __restrict__ bias, float* __restrict__ out) {
    __shared__ float ws[343];
    int tid = threadIdx.x;
    int c = blockIdx.y, b = blockIdx.z;
    for (int i = tid; i < 343; i += 256) ws[i] = w[c * 343 + i];
    __syncthreads();
    int s = blockIdx.x * 256 + tid;
    int z = s >> 10, y = (s >> 5) & 31, xx = s & 31;
    const float* ib = in + ((size_t)b * CCH + c) * SVOL;
    float acc = bias[c];
    for (int tz = 0; tz < 7; tz++) {
        int zz = z + 3 * (tz - 3); if (zz < 0 || zz >= 32) continue;
        for (int ty = 0; ty < 7; ty++) {
            int yy = y + 3 * (ty - 3); if (yy < 0 || yy >= 32) continue;
            #pragma unroll
            for (int tx = 0; tx < 7; tx++) {
                int xv = xx + 3 * (tx - 3); if (xv < 0 || xv >= 32) continue;
                acc += ws[(tz * 7 + ty) * 7 + tx] * ib[(zz * 32 + yy) * 32 + xv];
            }
        }
    }
    out[((size_t)b * CCH + c) * SVOL + s] = acc;
}

// ---- offset conv 3x3x3: 48 -> 81, ci-split 2 x out-split 3, atomic partials, NO bias ----
__global__ __launch_bounds__(256, 4)
void offconv_kernel(const float* __restrict__ a1, const float* __restrict__ w,
                    float* __restrict__ off) {
    __shared__ float ws[24 * 27];   // ws[cis*27+o]
    int tid = threadIdx.x;
    int go = blockIdx.y % 3;        // output group (27 outs)
    int gc = blockIdx.y / 3;        // ci group (24 ins)
    int b = blockIdx.z;
    int s = blockIdx.x * 256 + tid;
    int z = s >> 10, y = (s >> 5) & 31, xx = s & 31;
    const float* ib = a1 + ((size_t)b * CCH + gc * 24) * SVOL;
    float acc[27];
    #pragma unroll
    for (int o = 0; o < 27; o++) acc[o] = 0.f;
    for (int tap = 0; tap < 27; tap++) {
        __syncthreads();
        for (int i = tid; i < 24 * 27; i += 256) {
            int o = i % 27, cis = i / 27;
            ws[cis * 27 + o] = w[((go * 27 + o) * CCH + gc * 24 + cis) * 27 + tap];
        }
        __syncthreads();
        int dz = tap / 9 - 1, dy = (tap / 3) % 3 - 1, dx = tap % 3 - 1;
        int zz = z + dz, yy = y + dy, xv = xx + dx;
        bool ok = (zz >= 0 && zz < 32 && yy >= 0 && yy < 32 && xv >= 0 && xv < 32);
        if (ok) {
            int si = (zz * 32 + yy) * 32 + xv;
            for (int cis = 0; cis < 24; cis++) {
                float v = ib[(size_t)cis * SVOL + si];
                #pragma unroll
                for (int o = 0; o < 27; o++) acc[o] += ws[cis * 27 + o] * v;
            }
        }
    }
    float* ob = off + (size_t)b * 81 * SVOL + (size_t)(go * 27) * SVOL + s;
    #pragma unroll
    for (int o = 0; o < 27; o++) atomicAdd(&ob[(size_t)o * SVOL], acc[o]);
}

// ---- deformable conv 3x3x3: ci-split 4 (12 ch each), all 48 outputs, atomic partials, NO bias ----
// off buffer holds bias-less offsets; off_b added to coordinates here.
__global__ __launch_bounds__(256, 4)
void deform_kernel(const float* __restrict__ a1, const float* __restrict__ off,
                   const float* __restrict__ off_b,
                   const float* __restrict__ dcw, float* __restrict__ out) {
    __shared__ float ws[12 * CCH];  // ws[cis*48+o]
    int tid = threadIdx.x;
    int gc = blockIdx.y;            // ci group 0..3
    int b = blockIdx.z;
    int s = blockIdx.x * 256 + tid;
    int z = s >> 10, y = (s >> 5) & 31, xx = s & 31;
    const float* ib = a1 + ((size_t)b * CCH + gc * 12) * SVOL;
    const float* ob = off + (size_t)b * 81 * SVOL + s;
    float acc[CCH];
    #pragma unroll
    for (int o = 0; o < CCH; o++) acc[o] = 0.f;
    for (int k = 0; k < 27; k++) {
        __syncthreads();
        for (int i = tid; i < 12 * CCH; i += 256) {
            int o = i % CCH, cis = i / CCH;
            ws[cis * CCH + o] = dcw[((size_t)o * CCH + gc * 12 + cis) * 27 + k];
        }
        __syncthreads();
        int kd = k / 9 - 1, kh = (k / 3) % 3 - 1, kw = k % 3 - 1;
        float zf = (float)(z + kd) + ob[(size_t)(k * 3 + 0) * SVOL] + off_b[k * 3 + 0];
        float yf = (float)(y + kh) + ob[(size_t)(k * 3 + 1) * SVOL] + off_b[k * 3 + 1];
        float xf = (float)(xx + kw) + ob[(size_t)(k * 3 + 2) * SVOL] + off_b[k * 3 + 2];
        float z0 = floorf(zf), y0 = floorf(yf), x0 = floorf(xf);
        float tz = zf - z0, ty = yf - y0, tx = xf - x0;
        int iz0 = (int)z0, iy0 = (int)y0, ix0 = (int)x0;
        float cw[8]; int cidx[8];
        #pragma unroll
        for (int corner = 0; corner < 8; corner++) {
            int dz = corner >> 2, dy = (corner >> 1) & 1, dx = corner & 1;
            int zi = iz0 + dz, yi = iy0 + dy, xi = ix0 + dx;
            bool valid = (zi >= 0 && zi < 32 && yi >= 0 && yi < 32 && xi >= 0 && xi < 32);
            float wgt = (dz ? tz : 1.f - tz) * (dy ? ty : 1.f - ty) * (dx ? tx : 1.f - tx);
            cw[corner] = valid ? wgt : 0.f;
            int zc = min(max(zi, 0), 31), yc = min(max(yi, 0), 31), xc = min(max(xi, 0), 31);
            cidx[corner] = (zc * 32 + yc) * 32 + xc;
        }
        for (int cis = 0; cis < 12; cis++) {
            const float* p = ib + (size_t)cis * SVOL;
            float val = 0.f;
            #pragma unroll
            for (int corner = 0; corner < 8; corner++) val += cw[corner] * p[cidx[corner]];
            #pragma unroll
            for (int o = 0; o < CCH; o++) acc[o] += ws[cis * CCH + o] * val;
        }
    }
    float* op = out + (size_t)b * CCH * SVOL + s;
    #pragma unroll
    for (int o = 0; o < CCH; o++) atomicAdd(&op[(size_t)o * SVOL], acc[o]);
}

// ---- gate1: a2 = (c1 . dc + (c1b + c1 . dcb)) * u   (4 groups x 12) ----
__global__ __launch_bounds__(256, 4)
void gate1_kernel(const float* __restrict__ dc, const float* __restrict__ u,
                  const float* __restrict__ c1w, const float* __restrict__ c1b,
                  const float* __restrict__ dcb, float* __restrict__ a2buf) {
    __shared__ float w1[CCH * 12];
    __shared__ float cb[12];
    int tid = threadIdx.x;
    int g = blockIdx.y, b = blockIdx.z;
    for (int i = tid; i < CCH * 12; i += 256) {
        int o = i % 12, ci = i / 12;
        w1[ci * 12 + o] = c1w[(g * 12 + o) * CCH + ci];
    }
    if (tid < 12) {
        int ow = g * 12 + tid;
        float v = c1b[ow];
        for (int ci = 0; ci < CCH; ci++) v += c1w[ow * CCH + ci] * dcb[ci];
        cb[tid] = v;
    }
    __syncthreads();
    int s = blockIdx.x * 256 + tid;
    size_t base = (size_t)b * CCH * SVOL + s;
    float acc[12];
    #pragma unroll
    for (int o = 0; o < 12; o++) acc[o] = cb[o];
    for (int ci = 0; ci < CCH; ci++) {
        float v = dc[base + (size_t)ci * SVOL];
        #pragma unroll
        for (int o = 0; o < 12; o++) acc[o] += w1[ci * 12 + o] * v;
    }
    #pragma unroll
    for (int o = 0; o < 12; o++) {
        size_t oo = base + (size_t)(g * 12 + o) * SVOL;
        a2buf[oo] = acc[o] * u[oo];
    }
}

// ---- gate2: skip = x + gamma*(p2 . a2 + p2b + xn)  (4 groups x 12) ----
__global__ __launch_bounds__(256, 4)
void gate2_kernel(const float* __restrict__ a2buf, const float* __restrict__ xn,
                  const float* __restrict__ x,
                  const float* __restrict__ p2w, const float* __restrict__ p2b,
                  const float* __restrict__ gamma, float* __restrict__ skip) {
    __shared__ float w2[CCH * 12];
    int tid = threadIdx.x;
    int g = blockIdx.y, b = blockIdx.z;
    for (int i = tid; i < CCH * 12; i += 256) {
        int o = i % 12, ci = i / 12;
        w2[ci * 12 + o] = p2w[(g * 12 + o) * CCH + ci];
    }
    __syncthreads();
    int s = blockIdx.x * 256 + tid;
    size_t base = (size_t)b * CCH * SVOL + s;
    float acc[12];
    #pragma unroll
    for (int o = 0; o < 12; o++) acc[o] = p2b[g * 12 + o];
    for (int ci = 0; ci < CCH; ci++) {
        float v = a2buf[base + (size_t)ci * SVOL];
        #pragma unroll
        for (int o = 0; o < 12; o++) acc[o] += w2[ci * 12 + o] * v;
    }
    #pragma unroll
    for (int o = 0; o < 12; o++) {
        int oc = g * 12 + o;
        float vv = acc[o] + xn[base + (size_t)oc * SVOL];
        skip[base + (size_t)oc * SVOL] = x[base + (size_t)oc * SVOL] + gamma[oc] * vv;
    }
}

// ---- u1: 3x3x3 conv + BN1 + LeakyReLU (4 groups x 12) ----
__global__ __launch_bounds__(256, 4)
void u1_kernel(const float* __restrict__ in, const float* __restrict__ w,
               const float* __restrict__ bs, const float* __restrict__ bb,
               const float* __restrict__ bm, const float* __restrict__ bv,
               float* __restrict__ out) {
    __shared__ float ws[CCH * 12];
    int tid = threadIdx.x;
    int g = blockIdx.y, b = blockIdx.z;
    int s = blockIdx.x * 256 + tid;
    int z = s >> 10, y = (s >> 5) & 31, xx = s & 31;
    const float* ib = in + (size_t)b * CCH * SVOL;
    float acc[12];
    #pragma unroll
    for (int o = 0; o < 12; o++) acc[o] = 0.f;
    for (int tap = 0; tap < 27; tap++) {
        __syncthreads();
        for (int i = tid; i < CCH * 12; i += 256) {
            int o = i % 12, ci = i / 12;
            ws[ci * 12 + o] = w[((g * 12 + o) * CCH + ci) * 27 + tap];
        }
        __syncthreads();
        int dz = tap / 9 - 1, dy = (tap / 3) % 3 - 1, dx = tap % 3 - 1;
        int zz = z + dz, yy = y + dy, xv = xx + dx;
        bool ok = (zz >= 0 && zz < 32 && yy >= 0 && yy < 32 && xv >= 0 && xv < 32);
        if (ok) {
            int si = (zz * 32 + yy) * 32 + xv;
            for (int ci = 0; ci < CCH; ci++) {
                float v = ib[(size_t)ci * SVOL + si];
                #pragma unroll
                for (int o = 0; o < 12; o++) acc[o] += ws[ci * 12 + o] * v;
            }
        }
    }
    float* op = out + (size_t)b * CCH * SVOL + (size_t)(g * 12) * SVOL + s;
    #pragma unroll
    for (int o = 0; o < 12; o++) {
        int oc = g * 12 + o;
        float inv = rsqrtf(bv[oc] + 1e-5f);
        float h = (acc[o] - bm[oc]) * (bs[oc] * inv) + bb[oc];
        op[(size_t)o * SVOL] = h >= 0.f ? h : 0.01f * h;
    }
}

// ---- u2_bn: 3x3x3 conv + BN2 + (+skip) + LeakyReLU -> attn (4 groups x 12) ----
__global__ __launch_bounds__(256, 4)
void u2_bn_kernel(const float* __restrict__ h1, const float* __restrict__ skip,
                  const float* __restrict__ w,
                  const float* __restrict__ bs, const float* __restrict__ bb,
                  const float* __restrict__ bm, const float* __restrict__ bv,
                  float* __restrict__ attn) {
    __shared__ float ws[CCH * 12];
    int tid = threadIdx.x;
    int g = blockIdx.y, b = blockIdx.z;
    int s = blockIdx.x * 256 + tid;
    int z = s >> 10, y = (s >> 5) & 31, xx = s & 31;
    const float* ib = h1 + (size_t)b * CCH * SVOL;
    float acc[12];
    #pragma unroll
    for (int o = 0; o < 12; o++) acc[o] = 0.f;
    for (int tap = 0; tap < 27; tap++) {
        __syncthreads();
        for (int i = tid; i < CCH * 12; i += 256) {
            int o = i % 12, ci = i / 12;
            ws[ci * 12 + o] = w[((g * 12 + o) * CCH + ci) * 27 + tap];
        }
        __syncthreads();
        int dz = tap / 9 - 1, dy = (tap / 3) % 3 - 1, dx = tap % 3 - 1;
        int zz = z + dz, yy = y + dy, xv = xx + dx;
        bool ok = (zz >= 0 && zz < 32 && yy >= 0 && yy < 32 && xv >= 0 && xv < 32);
        if (ok) {
            int si = (zz * 32 + yy) * 32 + xv;
            for (int ci = 0; ci < CCH; ci++) {
                float v = ib[(size_t)ci * SVOL + si];
                #pragma unroll
                for (int o = 0; o < 12; o++) acc[o] += ws[ci * 12 + o] * v;
            }
        }
    }
    size_t base = (size_t)b * CCH * SVOL + s;
    #pragma unroll
    for (int o = 0; o < 12; o++) {
        int oc = g * 12 + o;
        float inv = rsqrtf(bv[oc] + 1e-5f);
        float h = (acc[o] - bm[oc]) * (bs[oc] * inv) + bb[oc];
        float a = h + skip[base + (size_t)oc * SVOL];
        attn[base + (size_t)oc * SVOL] = a >= 0.f ? a : 0.01f * a;
    }
}

// ---- pr_final: out = skip + pr(attn)  (4 groups x 12) ----
__global__ __launch_bounds__(256, 4)
void pr_final_kernel(const float* __restrict__ attn, const float* __restrict__ skip,
                     const float* __restrict__ prw, const float* __restrict__ prb,
                     float* __restrict__ out) {
    __shared__ float pw[CCH * 12];
    int tid = threadIdx.x;
    int g = blockIdx.y, b = blockIdx.z;
    for (int i = tid; i < CCH * 12; i += 256) {
        int o = i % 12, ci = i / 12;
        pw[ci * 12 + o] = prw[(g * 12 + o) * CCH + ci];
    }
    __syncthreads();
    int s = blockIdx.x * 256 + tid;
    size_t base = (size_t)b * CCH * SVOL + s;
    float acc[12];
    #pragma unroll
    for (int o = 0; o < 12; o++) acc[o] = prb[g * 12 + o];
    for (int ci = 0; ci < CCH; ci++) {
        float v = attn[base + (size_t)ci * SVOL];
        #pragma unroll
        for (int o = 0; o < 12; o++) acc[o] += pw[ci * 12 + o] * v;
    }
    #pragma unroll
    for (int o = 0; o < 12; o++) {
        int oc = g * 12 + o;
        out[base + (size_t)oc * SVOL] = skip[base + (size_t)oc * SVOL] + acc[o];
    }
}

extern "C" void kernel_launch(void* const* d_in, const int* in_sizes, int n_in,
                              void* d_out, int out_size, void* d_ws, size_t ws_size,
                              hipStream_t stream) {
    (void)in_sizes; (void)n_in; (void)out_size; (void)ws_size;
    const float* x     = (const float*)d_in[0];
    const float* ln_s  = (const float*)d_in[1];
    const float* ln_b  = (const float*)d_in[2];
    const float* gamma = (const float*)d_in[3];
    const float* p1_w  = (const float*)d_in[4];
    const float* p1_b  = (const float*)d_in[5];
    const float* p2_w  = (const float*)d_in[6];
    const float* p2_b  = (const float*)d_in[7];
    const float* c0_w  = (const float*)d_in[8];
    const float* c0_b  = (const float*)d_in[9];
    const float* cs_w  = (const float*)d_in[10];
    const float* cs_b  = (const float*)d_in[11];
    const float* off_w = (const float*)d_in[12];
    const float* off_b = (const float*)d_in[13];
    const float* dc_w  = (const float*)d_in[14];
    const float* dc_b  = (const float*)d_in[15];
    const float* c1_w  = (const float*)d_in[16];
    const float* c1_b  = (const float*)d_in[17];
    const float* u1_w  = (const float*)d_in[18];
    const float* bn1_s = (const float*)d_in[19];
    const float* bn1_b = (const float*)d_in[20];
    const float* bn1_m = (const float*)d_in[21];
    const float* bn1_v = (const float*)d_in[22];
    const float* u2_w  = (const float*)d_in[23];
    const float* bn2_s = (const float*)d_in[24];
    const float* bn2_b = (const float*)d_in[25];
    const float* bn2_m = (const float*)d_in[26];
    const float* bn2_v = (const float*)d_in[27];
    const float* pr_w  = (const float*)d_in[28];
    const float* pr_b  = (const float*)d_in[29];
    float* out = (float*)d_out;

    float* wsf = (float*)d_ws;
    const size_t TS = (size_t)NB * CCH * SVOL;   // 3,145,728 floats
    float* xn   = out;            // d_out doubles as xn (dead before final write)
    float* ubuf = wsf;            // u (gelu out), later h1 (u1 out)
    float* bufA = wsf + TS;       // dw5 out -> deform partials -> attn
    float* bufB = wsf + 2 * TS;   // dw7 out (a1) -> skip
    float* offb = wsf + 3 * TS;   // offset partials [B,81,S]; later a2
    // ws use: 3*TS + NB*81*SVOL = 14,745,600 floats = 59.0 MB

    dim3 blk(256);
    dim3 gpos(SVOL / 256, NB);
    dim3 g4(SVOL / 256, 4, NB);
    dim3 g6(SVOL / 256, 6, NB);
    dim3 gdw(SVOL / 256, CCH, NB);

    hipLaunchKernelGGL(ln_kernel,       gpos, blk, 0, stream, x, ln_s, ln_b, xn);
    hipLaunchKernelGGL(p1_gelu_kernel,  g4,   blk, 0, stream, xn, p1_w, p1_b, ubuf);
    hipLaunchKernelGGL(dw5_kernel,      gdw,  blk, 0, stream, ubuf, c0_w, c0_b, bufA);
    hipLaunchKernelGGL(dw7_kernel,      gdw,  blk, 0, stream, bufA, cs_w, cs_b, bufB);
    hipMemsetAsync(offb, 0, (size_t)NB * 81 * SVOL * sizeof(float), stream);
    hipLaunchKernelGGL(offconv_kernel,  g6,   blk, 0, stream, bufB, off_w, offb);
    hipMemsetAsync(bufA, 0, TS * sizeof(float), stream);
    hipLaunchKernelGGL(deform_kernel,   g4,   blk, 0, stream, bufB, offb, off_b, dc_w, bufA);
    hipLaunchKernelGGL(gate1_kernel,    g4,   blk, 0, stream, bufA, ubuf, c1_w, c1_b, dc_b, offb);
    hipLaunchKernelGGL(gate2_kernel,    g4,   blk, 0, stream, offb, xn, x, p2_w, p2_b, gamma, bufB);
    hipLaunchKernelGGL(u1_kernel,       g4,   blk, 0, stream, bufB, u1_w,
                       bn1_s, bn1_b, bn1_m, bn1_v, ubuf);
    hipLaunchKernelGGL(u2_bn_kernel,    g4,   blk, 0, stream, ubuf, bufB, u2_w,
                       bn2_s, bn2_b, bn2_m, bn2_v, bufA);
    hipLaunchKernelGGL(pr_final_kernel, g4,   blk, 0, stream, bufA, bufB, pr_w, pr_b, out);
}